// Round 9
// baseline (893.310 us; speedup 1.0000x reference)
//
#include <hip/hip_runtime.h>
#include <cstdint>
#include <cstddef>

typedef uint16_t u16;
typedef uint32_t u32;
typedef __bf16 bf16x8 __attribute__((ext_vector_type(8)));
typedef float f32x4 __attribute__((ext_vector_type(4)));

#define TBLK 2048
#define KD 512
#define NH 8
#define MROWS 8192      // 4 batches x 2048

__device__ __forceinline__ u16 f2b(float f){
  u32 u = __builtin_bit_cast(u32, f);
  u = (u + 0x7fffu + ((u >> 16) & 1u)) >> 16;
  return (u16)u;
}

__device__ __forceinline__ float gelu_tanh(float x){
  float x3 = x*x*x;
  float t = tanhf(0.7978845608028654f*(x + 0.044715f*x3));
  return 0.5f*x*(1.0f + t);
}

// async global->LDS, 16B per lane; LDS dest is wave-uniform base + lane*16
__device__ __forceinline__ void glds16(const u16* g, u16* l){
  __builtin_amdgcn_global_load_lds((const __attribute__((address_space(1))) void*)g,
                                   (__attribute__((address_space(3))) void*)l,
                                   16, 0, 0);
}

// ---------------- elementwise f32 -> bf16 ----------------
__global__ void to_bf16_kernel(const float* __restrict__ in, u16* __restrict__ out, int n4){
  int i = blockIdx.x*256 + threadIdx.x;
  if (i >= n4) return;
  size_t base = (size_t)i*4;
  float4 v = *(const float4*)(in + base);
  uint2 pk;
  pk.x = (u32)f2b(v.x) | ((u32)f2b(v.y) << 16);
  pk.y = (u32)f2b(v.z) | ((u32)f2b(v.w) << 16);
  *(uint2*)(out + base) = pk;
}

// ---- transpose + convert: in R x C f32 -> out C x R bf16 ----
template<bool PERM>
__global__ void transpose_to_bf16(const float* __restrict__ in, u16* __restrict__ out, int R, int C){
  __shared__ float tile[64][65];
  int bc = blockIdx.x*64, br = blockIdx.y*64;
  int tx = threadIdx.x & 63, ty = threadIdx.x >> 6;
  #pragma unroll
  for (int i = 0; i < 64; i += 4)
    tile[ty+i][tx] = in[(size_t)(br+ty+i)*C + bc + tx];
  __syncthreads();
  #pragma unroll
  for (int i = 0; i < 64; i += 4){
    int n = bc + ty + i;
    int np = PERM ? ((n & 7)*512 + (n >> 3)) : n;
    out[(size_t)np*R + br + tx] = f2b(tile[tx][ty+i]);
  }
}

// merged QKV weight transpose (z selects Wq/Wk/Wv), PERM row order
__global__ void transpose_qkv3(const float* __restrict__ wq, const float* __restrict__ wk,
                               const float* __restrict__ wv, u16* __restrict__ oq,
                               u16* __restrict__ ok, u16* __restrict__ ov){
  __shared__ float tile[64][65];
  const float* in = (blockIdx.z == 0) ? wq : (blockIdx.z == 1 ? wk : wv);
  u16* out = (blockIdx.z == 0) ? oq : (blockIdx.z == 1 ? ok : ov);
  int bc = blockIdx.x*64, br = blockIdx.y*64;   // C=4096, R=512
  int tx = threadIdx.x & 63, ty = threadIdx.x >> 6;
  #pragma unroll
  for (int i = 0; i < 64; i += 4)
    tile[ty+i][tx] = in[(size_t)(br+ty+i)*4096 + bc + tx];
  __syncthreads();
  #pragma unroll
  for (int i = 0; i < 64; i += 4){
    int n = bc + ty + i;
    int np = (n & 7)*512 + (n >> 3);
    out[(size_t)np*512 + br + tx] = f2b(tile[tx][ty+i]);
  }
}

// ---------------- GEMM 128xBN (Wu, FF2) ----------------
// MODE 2: out32[row*512+col] = v + bias[col]          (Wu)
// MODE 4: out32[row*512+col] = v + bias[col] + resid  (FF2)
template<int MODE, int BN>
__launch_bounds__(256, 2)
__global__ void gemm_bf16(const u16* __restrict__ A, int lda,
                          const u16* __restrict__ Bt, int M, int N, int K,
                          const float* __restrict__ bias, const float* __restrict__ resid,
                          float scale, u16* __restrict__ out16, float* __restrict__ out32)
{
  __shared__ alignas(16) u16 At[2][128*32];
  __shared__ alignas(16) u16 Bs[2][BN*32];
  constexpr int MT = (BN == 128) ? 4 : 2;
  constexpr int BU = (BN == 128) ? 2 : 1;
  int ntn = N / BN;
  int tm = blockIdx.x / ntn;
  int tn = blockIdx.x - tm*ntn;
  int m0 = tm << 7, n0 = tn*BN;
  int tid = threadIdx.x;
  int lane = tid & 63;
  int w = tid >> 6;
  int wr = (BN == 128) ? (w >> 1) : w;
  int wc = (BN == 128) ? (w & 1) : 0;
  int rl = lane & 15, gr = lane >> 4;
  int srow = lane >> 2;
  int scol = (lane & 3) ^ ((lane >> 3) & 3);

  f32x4 acc[MT][4];
  #pragma unroll
  for (int m = 0; m < MT; ++m)
    #pragma unroll
    for (int n = 0; n < 4; ++n)
      #pragma unroll
      for (int r = 0; r < 4; ++r) acc[m][n][r] = 0.f;

  auto stage = [&](int buf, int k0){
    #pragma unroll
    for (int i = 0; i < 2; ++i){
      int u = w*2 + i;
      glds16(A + (size_t)(m0 + u*16 + srow)*lda + k0 + scol*8, &At[buf][u*512]);
    }
    #pragma unroll
    for (int i = 0; i < BU; ++i){
      int u = w*BU + i;
      glds16(Bt + (size_t)(n0 + u*16 + srow)*K + k0 + scol*8, &Bs[buf][u*512]);
    }
  };

  stage(0, 0);
  int nsteps = K >> 5;
  for (int s = 0; s < nsteps; ++s){
    int cur = s & 1;
    __syncthreads();
    if (s + 1 < nsteps) stage(cur ^ 1, (s + 1)*32);
    bf16x8 af[MT], bfv[4];
    #pragma unroll
    for (int m = 0; m < MT; ++m){
      int row = wr*MT*16 + m*16 + rl;
      af[m] = *(const bf16x8*)(&At[cur][row*32 + ((gr ^ ((row >> 1) & 3))*8)]);
    }
    #pragma unroll
    for (int n = 0; n < 4; ++n){
      int row = wc*64 + n*16 + rl;
      bfv[n] = *(const bf16x8*)(&Bs[cur][row*32 + ((gr ^ ((row >> 1) & 3))*8)]);
    }
    __builtin_amdgcn_s_setprio(1);
    #pragma unroll
    for (int m = 0; m < MT; ++m)
      #pragma unroll
      for (int n = 0; n < 4; ++n)
        acc[m][n] = __builtin_amdgcn_mfma_f32_16x16x32_bf16(af[m], bfv[n], acc[m][n], 0, 0, 0);
    __builtin_amdgcn_s_setprio(0);
  }

  #pragma unroll
  for (int m = 0; m < MT; ++m){
    #pragma unroll
    for (int n = 0; n < 4; ++n){
      int col = n0 + wc*64 + n*16 + rl;
      #pragma unroll
      for (int r = 0; r < 4; ++r){
        int row = m0 + wr*MT*16 + m*16 + gr*4 + r;
        float v = acc[m][n][r];
        if (MODE == 2){
          out32[(size_t)row*512 + col] = v + bias[col];
        } else {
          out32[(size_t)row*512 + col] = v + bias[col] + resid[(size_t)row*512 + col];
        }
      }
    }
  }
}

// ---------------- GEMM 256x128 (QKV fused, FF1) ----------------
// 4 waves as 2x2; each wave 128x64 output (MT=8 x 4). 32 MFMA : 12 ds_read per K-step.
// MODE 3: out16[row*2048+col] = bf16(gelu(v+bias))    (FF1)
// MODE 5: fused QKV split into out16/o2_16/o3_16 with qscale on Q,K
template<int MODE>
__launch_bounds__(256, 2)
__global__ void gemm256_bf16(const u16* __restrict__ A, int lda,
                             const u16* __restrict__ Bt, int M, int N, int K,
                             const float* __restrict__ bias, float scale,
                             u16* __restrict__ out16,
                             u16* __restrict__ o2_16, u16* __restrict__ o3_16)
{
  __shared__ alignas(16) u16 At[2][256*32];   // 2 x 16KB
  __shared__ alignas(16) u16 Bs[2][128*32];   // 2 x 8KB
  int ntn = N >> 7;
  int tm = blockIdx.x / ntn;
  int tn = blockIdx.x - tm*ntn;
  int m0 = tm << 8, n0 = tn << 7;
  int tid = threadIdx.x;
  int lane = tid & 63;
  int w = tid >> 6, wr = w >> 1, wc = w & 1;
  int rl = lane & 15, gr = lane >> 4;
  int srow = lane >> 2;
  int scol = (lane & 3) ^ ((lane >> 3) & 3);

  f32x4 acc[8][4];
  #pragma unroll
  for (int m = 0; m < 8; ++m)
    #pragma unroll
    for (int n = 0; n < 4; ++n)
      #pragma unroll
      for (int r = 0; r < 4; ++r) acc[m][n][r] = 0.f;

  auto stage = [&](int buf, int k0){
    #pragma unroll
    for (int i = 0; i < 4; ++i){
      int u = w*4 + i;
      glds16(A + (size_t)(m0 + u*16 + srow)*lda + k0 + scol*8, &At[buf][u*512]);
    }
    #pragma unroll
    for (int i = 0; i < 2; ++i){
      int u = w*2 + i;
      glds16(Bt + (size_t)(n0 + u*16 + srow)*K + k0 + scol*8, &Bs[buf][u*512]);
    }
  };

  stage(0, 0);
  int nsteps = K >> 5;
  for (int s = 0; s < nsteps; ++s){
    int cur = s & 1;
    __syncthreads();
    if (s + 1 < nsteps) stage(cur ^ 1, (s + 1)*32);
    bf16x8 af[8], bfv[4];
    #pragma unroll
    for (int m = 0; m < 8; ++m){
      int row = wr*128 + m*16 + rl;
      af[m] = *(const bf16x8*)(&At[cur][row*32 + ((gr ^ ((row >> 1) & 3))*8)]);
    }
    #pragma unroll
    for (int n = 0; n < 4; ++n){
      int row = wc*64 + n*16 + rl;
      bfv[n] = *(const bf16x8*)(&Bs[cur][row*32 + ((gr ^ ((row >> 1) & 3))*8)]);
    }
    __builtin_amdgcn_s_setprio(1);
    #pragma unroll
    for (int m = 0; m < 8; ++m)
      #pragma unroll
      for (int n = 0; n < 4; ++n)
        acc[m][n] = __builtin_amdgcn_mfma_f32_16x16x32_bf16(af[m], bfv[n], acc[m][n], 0, 0, 0);
    __builtin_amdgcn_s_setprio(0);
  }

  #pragma unroll
  for (int m = 0; m < 8; ++m){
    #pragma unroll
    for (int n = 0; n < 4; ++n){
      int col = n0 + wc*64 + n*16 + rl;
      #pragma unroll
      for (int r = 0; r < 4; ++r){
        int row = m0 + wr*128 + m*16 + gr*4 + r;
        float v = acc[m][n][r];
        if (MODE == 3){
          out16[(size_t)row*2048 + col] = f2b(gelu_tanh(v + bias[col]));
        } else {  // MODE 5
          u16* dst = (col < 4096) ? out16 : (col < 8192 ? o2_16 : o3_16);
          float sc = (col < 8192) ? scale : 1.0f;
          dst[(size_t)row*4096 + (col & 4095)] = f2b(v*sc);
        }
      }
    }
  }
}

// ---------------- V transpose: vg[(bl*2048+t)*4096 + h*512+d] -> vtb[bh][d][t] ----------------
__global__ void vtrans_kernel(const u16* __restrict__ vg, u16* __restrict__ vtb){
  __shared__ alignas(16) u16 tile[64][72];
  int t0 = blockIdx.x*64;
  int d0 = blockIdx.y*64;
  int bh = blockIdx.z;
  int bl = bh >> 3, h = bh & 7;
  int tid = threadIdx.x;
  #pragma unroll
  for (int it = 0; it < 4; ++it){
    int id = it*256 + tid;
    int r = id >> 4, cq = id & 15;
    *(uint2*)(&tile[r][cq*4]) =
        *(const uint2*)(vg + (size_t)(bl*TBLK + t0 + r)*4096 + h*512 + d0 + cq*4);
  }
  __syncthreads();
  #pragma unroll
  for (int it = 0; it < 2; ++it){
    int id = it*256 + tid;
    int dr = id >> 3, tg = id & 7;
    alignas(16) u16 tmp[8];
    #pragma unroll
    for (int j = 0; j < 8; ++j) tmp[j] = tile[tg*8 + j][dr];
    *(uint4*)(vtb + ((size_t)bh*512 + d0 + dr)*TBLK + t0 + tg*8) = *(const uint4*)tmp;
  }
}

// ---------------- flash attention (round-6 schedule) ----------------
__launch_bounds__(512, 2)
__global__ void flash_attn(const u16* __restrict__ qg, const u16* __restrict__ kg,
                           const u16* __restrict__ vtb, u16* __restrict__ ctx)
{
  int bh = blockIdx.x;
  int qt = blockIdx.y;
  int bl = bh >> 3, h = bh & 7;
  int tid = threadIdx.x;
  int lane = tid & 63, w = tid >> 6;
  int rl = lane & 15, gr = lane >> 4;
  const u16* Qb = qg + (size_t)bl*TBLK*4096 + h*512;
  const u16* Kb = kg + (size_t)bl*TBLK*4096 + h*512;
  const u16* Vb = vtb + (size_t)bh*512*TBLK;

  __shared__ alignas(16) u16 Ka[2][32*512];
  __shared__ alignas(16) u16 Va[2][512*32];
  __shared__ alignas(16) u16 Pl[8][512];

  int q0 = qt*128 + w*16;
  bf16x8 qf[16];
  #pragma unroll
  for (int kc = 0; kc < 16; ++kc)
    qf[kc] = *(const bf16x8*)(Qb + (size_t)(q0 + rl)*4096 + kc*32 + gr*8);

  f32x4 o[32];
  #pragma unroll
  for (int n = 0; n < 32; ++n)
    #pragma unroll
    for (int r = 0; r < 4; ++r) o[n][r] = 0.f;
  float mrow[4] = {-1e30f, -1e30f, -1e30f, -1e30f};
  float lsum[4] = {0.f, 0.f, 0.f, 0.f};

  auto stage = [&](int buf, int s0){
    #pragma unroll
    for (int i = 0; i < 4; ++i){
      int wl = w*4 + i;
      glds16(Kb + (size_t)(s0 + wl)*4096 + (size_t)((lane ^ (wl & 7))*8),
             &Ka[buf][wl*512]);
      int d = wl*16 + (lane >> 2);
      int oj = (lane & 3) ^ ((d >> 1) & 3);
      glds16(Vb + (size_t)d*TBLK + s0 + oj*8,
             &Va[buf][wl*512]);
    }
  };

  stage(0, 0);

  for (int t = 0; t < 64; ++t){
    int cur = t & 1;
    __syncthreads();                          // vmcnt(0) drain -> buf[cur] ready+visible

    // QK^T
    f32x4 sA[2];
    #pragma unroll
    for (int n = 0; n < 2; ++n)
      #pragma unroll
      for (int r = 0; r < 4; ++r) sA[n][r] = 0.f;
    __builtin_amdgcn_s_setprio(1);
    #pragma unroll
    for (int kc = 0; kc < 16; ++kc){
      #pragma unroll
      for (int n = 0; n < 2; ++n){
        int rowS = n*16 + rl;
        bf16x8 kf = *(const bf16x8*)(&Ka[cur][rowS*512 + (((kc*4 + gr) ^ (rowS & 7))*8)]);
        sA[n] = __builtin_amdgcn_mfma_f32_16x16x32_bf16(qf[kc], kf, sA[n], 0, 0, 0);
      }
    }
    __builtin_amdgcn_s_setprio(0);

    if (t < 63) stage(cur ^ 1, (t + 1)*32);   // async prefetch; drains at next barrier

    // lazy-max online softmax
    bool updl = false;
    #pragma unroll
    for (int n = 0; n < 2; ++n)
      #pragma unroll
      for (int r = 0; r < 4; ++r) updl |= (sA[n][r] > mrow[r] + 8.0f);
    if (__any(updl)){
      float pm[4], fr[4];
      #pragma unroll
      for (int r = 0; r < 4; ++r) pm[r] = fmaxf(sA[0][r], sA[1][r]);
      #pragma unroll
      for (int m = 1; m < 16; m <<= 1)
        #pragma unroll
        for (int r = 0; r < 4; ++r) pm[r] = fmaxf(pm[r], __shfl_xor(pm[r], m));
      #pragma unroll
      for (int r = 0; r < 4; ++r){
        float mn = fmaxf(mrow[r], pm[r]);
        fr[r] = __expf(mrow[r] - mn);
        mrow[r] = mn;
        lsum[r] *= fr[r];
      }
      #pragma unroll
      for (int n = 0; n < 32; ++n)
        #pragma unroll
        for (int r = 0; r < 4; ++r) o[n][r] *= fr[r];
    }

    float p0[4], p1[4];
    #pragma unroll
    for (int r = 0; r < 4; ++r){
      p0[r] = __expf(sA[0][r] - mrow[r]);
      p1[r] = __expf(sA[1][r] - mrow[r]);
      lsum[r] += p0[r] + p1[r];
    }

    u16* pw = &Pl[w][0];
    #pragma unroll
    for (int r = 0; r < 4; ++r){
      int tq = gr*4 + r;
      pw[tq*32 + rl]      = f2b(p0[r]);
      pw[tq*32 + 16 + rl] = f2b(p1[r]);
    }
    asm volatile("s_waitcnt lgkmcnt(0)" ::: "memory");
    bf16x8 pa = *(const bf16x8*)(pw + rl*32 + gr*8);

    // PV
    __builtin_amdgcn_s_setprio(1);
    #pragma unroll
    for (int n = 0; n < 32; ++n){
      int rowV = n*16 + rl;
      bf16x8 vf = *(const bf16x8*)(&Va[cur][rowV*32 + ((gr ^ ((rowV >> 1) & 3))*8)]);
      o[n] = __builtin_amdgcn_mfma_f32_16x16x32_bf16(pa, vf, o[n], 0, 0, 0);
    }
    __builtin_amdgcn_s_setprio(0);
  }

  #pragma unroll
  for (int m = 1; m < 16; m <<= 1)
    #pragma unroll
    for (int r = 0; r < 4; ++r) lsum[r] += __shfl_xor(lsum[r], m);

  #pragma unroll
  for (int n = 0; n < 32; ++n){
    int d = n*16 + rl;
    #pragma unroll
    for (int r = 0; r < 4; ++r){
      int tq = q0 + gr*4 + r;
      float v = o[n][r] / lsum[r];
      ctx[((size_t)(bl*TBLK + tq))*4096 + h*512 + d] = f2b(v);
    }
  }
}

// ---------------- LayerNorm over (T,k) per batch ----------------
__global__ void reduce_ms(const float* __restrict__ in, float* __restrict__ part, int nblk){
  int b = blockIdx.y;
  const float4* p = (const float4*)(in + (size_t)b*TBLK*KD);
  int n4 = TBLK*KD/4;
  float s = 0.f, s2 = 0.f;
  for (int i = blockIdx.x*blockDim.x + threadIdx.x; i < n4; i += nblk*blockDim.x){
    float4 v = p[i];
    s  += v.x + v.y + v.z + v.w;
    s2 += v.x*v.x + v.y*v.y + v.z*v.z + v.w*v.w;
  }
  #pragma unroll
  for (int m = 1; m < 64; m <<= 1){ s += __shfl_xor(s, m); s2 += __shfl_xor(s2, m); }
  __shared__ float sh[8];
  int w = threadIdx.x >> 6;
  if ((threadIdx.x & 63) == 0){ sh[w] = s; sh[4 + w] = s2; }
  __syncthreads();
  if (threadIdx.x == 0){
    float a = 0.f, a2 = 0.f;
    for (int i = 0; i < 4; ++i){ a += sh[i]; a2 += sh[4 + i]; }
    part[((size_t)b*nblk + blockIdx.x)*2]     = a;
    part[((size_t)b*nblk + blockIdx.x)*2 + 1] = a2;
  }
}

__global__ void finalize_ms(const float* __restrict__ part, float* __restrict__ stats, int nblk){
  int b = blockIdx.x;
  float s = 0.f, s2 = 0.f;
  for (int i = threadIdx.x; i < nblk; i += 64){
    s  += part[((size_t)b*nblk + i)*2];
    s2 += part[((size_t)b*nblk + i)*2 + 1];
  }
  #pragma unroll
  for (int m = 1; m < 64; m <<= 1){ s += __shfl_xor(s, m); s2 += __shfl_xor(s2, m); }
  if (threadIdx.x == 0){
    float inv_n = 1.0f/((float)TBLK*KD);
    float mean = s*inv_n;
    float var = s2*inv_n - mean*mean;
    stats[b*2] = mean;
    stats[b*2 + 1] = 1.0f/sqrtf(var + 1e-5f);
  }
}

__global__ void ln1_apply(const float* __restrict__ attn, const float* __restrict__ x,
                          const float* __restrict__ stats, const float* __restrict__ gs,
                          const float* __restrict__ go, float* __restrict__ x1f,
                          u16* __restrict__ x1b){
  int g = blockIdx.x*256 + threadIdx.x;
  size_t base = (size_t)g*4;
  int b = (int)(base >> 20);
  int col = (int)(base & (KD - 1));
  float mean = stats[b*2], inv = stats[b*2 + 1];
  float4 a  = *(const float4*)(attn + base);
  float4 xr = *(const float4*)(x + base);
  float4 sc = *(const float4*)(gs + col);
  float4 of = *(const float4*)(go + col);
  float4 r;
  r.x = sc.x*(a.x - mean)*inv + of.x + xr.x;
  r.y = sc.y*(a.y - mean)*inv + of.y + xr.y;
  r.z = sc.z*(a.z - mean)*inv + of.z + xr.z;
  r.w = sc.w*(a.w - mean)*inv + of.w + xr.w;
  *(float4*)(x1f + base) = r;
  uint2 pk;
  pk.x = (u32)f2b(r.x) | ((u32)f2b(r.y) << 16);
  pk.y = (u32)f2b(r.z) | ((u32)f2b(r.w) << 16);
  *(uint2*)(x1b + base) = pk;
}

__global__ void ln2_apply(const float* __restrict__ y, const float* __restrict__ stats,
                          const float* __restrict__ gs, const float* __restrict__ go,
                          float* __restrict__ outp){
  int g = blockIdx.x*256 + threadIdx.x;
  size_t base = (size_t)g*4;
  int b = (int)(base >> 20);
  int col = (int)(base & (KD - 1));
  float mean = stats[b*2], inv = stats[b*2 + 1];
  float4 v  = *(const float4*)(y + base);
  float4 sc = *(const float4*)(gs + col);
  float4 of = *(const float4*)(go + col);
  float4 r;
  r.x = sc.x*(v.x - mean)*inv + of.x;
  r.y = sc.y*(v.y - mean)*inv + of.y;
  r.z = sc.z*(v.z - mean)*inv + of.z;
  r.w = sc.w*(v.w - mean)*inv + of.w;
  *(float4*)(outp + base) = r;
}

extern "C" void kernel_launch(void* const* d_in, const int* in_sizes, int n_in,
                              void* d_out, int out_size, void* d_ws, size_t ws_size,
                              hipStream_t stream)
{
  const float* x  = (const float*)d_in[0];
  const float* Wq = (const float*)d_in[1];
  const float* Wk = (const float*)d_in[2];
  const float* Wv = (const float*)d_in[3];
  const float* Wu = (const float*)d_in[4];
  const float* bu = (const float*)d_in[5];
  const float* g1 = (const float*)d_in[6];
  const float* o1 = (const float*)d_in[7];
  const float* W1 = (const float*)d_in[8];
  const float* b1 = (const float*)d_in[9];
  const float* W2 = (const float*)d_in[10];
  const float* b2 = (const float*)d_in[11];
  const float* g2 = (const float*)d_in[12];
  const float* o2 = (const float*)d_in[13];
  float* outp = (float*)d_out;
  (void)in_sizes; (void)n_in; (void)out_size;

  char* ws = (char*)d_ws;
  size_t off = 0;
  auto take = [&](size_t bytes)->char*{
    char* p = ws + off; off += (bytes + 255) & ~(size_t)255; return p;
  };
  u16* x16 = (u16*)take((size_t)MROWS*KD*2);
  u16* wqt = (u16*)take((size_t)4096*512*2);
  u16* wkt = (u16*)take((size_t)4096*512*2);
  u16* wvt = (u16*)take((size_t)4096*512*2);
  u16* wut = (u16*)take((size_t)512*4096*2);
  u16* w1t = (u16*)take((size_t)2048*512*2);
  u16* w2t = (u16*)take((size_t)512*2048*2);
  float* red = (float*)take((size_t)(4*256*2 + 8)*4);
  float* stats = red + 4*256*2;
  size_t fixed_end = off;

  size_t need1 = fixed_end + 4*((size_t)8192*8192 + 256);
  int cm = (ws_size >= need1) ? 8192 : 4096;
  int nchunks = MROWS / cm;
  size_t big = (size_t)cm*8192;
  u16* qg  = (u16*)take(big);
  u16* kg  = (u16*)take(big);
  u16* vg  = (u16*)take(big);
  u16* vtb = (u16*)take(big);

  // lifetime-disjoint aliases
  u16* ctx    = vg;
  char* qgc   = (char*)qg;
  float* attn = (float*)qgc;
  float* x1f  = (float*)(qgc + (size_t)cm*2048);
  u16*   x1b  = (u16*) (qgc + (size_t)cm*4096);
  float* yb   = (float*)(qgc + (size_t)cm*5120);
  u16*   fwd  = kg;

  const float qscale = 0.21022410381342865f;  // 512^(-1/4)

  to_bf16_kernel<<<dim3(4096), dim3(256), 0, stream>>>(x, x16, MROWS*KD/4);
  transpose_qkv3<<<dim3(64, 8, 3), dim3(256), 0, stream>>>(Wq, Wk, Wv, wqt, wkt, wvt);
  transpose_to_bf16<false><<<dim3(8, 64), dim3(256), 0, stream>>>(Wu, wut, 4096, 512);
  transpose_to_bf16<false><<<dim3(32, 8), dim3(256), 0, stream>>>(W1, w1t, 512, 2048);
  transpose_to_bf16<false><<<dim3(8, 32), dim3(256), 0, stream>>>(W2, w2t, 2048, 512);

  int nb = cm / TBLK;
  int nbh = nb * NH;
  for (int chunk = 0; chunk < nchunks; ++chunk){
    const u16* xc  = x16 + (size_t)chunk*cm*KD;
    const float* xf = x  + (size_t)chunk*cm*KD;

    // fused QKV projection, 256x128 tiles: Bt = [wqt|wkt|wvt], N = 12288
    gemm256_bf16<5><<<dim3((cm/256)*96), dim3(256), 0, stream>>>(xc, 512, wqt, cm, 12288, 512,
                                                        nullptr, qscale, qg, kg, vg);
    vtrans_kernel<<<dim3(32, 8, nbh), dim3(256), 0, stream>>>(vg, vtb);
    flash_attn<<<dim3(nbh, 16), dim3(512), 0, stream>>>(qg, kg, vtb, ctx);

    gemm_bf16<2,64><<<dim3((cm/128)*8), dim3(256), 0, stream>>>(ctx, 4096, wut, cm, 512, 4096,
                                                       bu, nullptr, 1.0f, nullptr, attn);
    reduce_ms<<<dim3(256, nb), dim3(256), 0, stream>>>(attn, red, 256);
    finalize_ms<<<dim3(nb), dim3(64), 0, stream>>>(red, stats, 256);
    ln1_apply<<<dim3(cm/2), dim3(256), 0, stream>>>(attn, xf, stats, g1, o1, x1f, x1b);

    gemm256_bf16<3><<<dim3((cm/256)*16), dim3(256), 0, stream>>>(x1b, 512, w1t, cm, 2048, 512,
                                                        b1, 1.0f, fwd, nullptr, nullptr);
    gemm_bf16<4,64><<<dim3((cm/128)*8), dim3(256), 0, stream>>>(fwd, 2048, w2t, cm, 512, 2048,
                                                       b2, x1f, 1.0f, nullptr, yb);
    reduce_ms<<<dim3(256, nb), dim3(256), 0, stream>>>(yb, red, 256);
    finalize_ms<<<dim3(nb), dim3(64), 0, stream>>>(red, stats, 256);
    ln2_apply<<<dim3(cm/2), dim3(256), 0, stream>>>(yb, stats, g2, o2, outp + (size_t)chunk*cm*KD);
  }
}

// Round 11
// 761.566 us; speedup vs baseline: 1.1730x; 1.1730x over previous
//
#include <hip/hip_runtime.h>
#include <cstdint>
#include <cstddef>

typedef uint16_t u16;
typedef uint32_t u32;
typedef unsigned char u8;
typedef long long i64;
typedef __bf16 bf16x8 __attribute__((ext_vector_type(8)));
typedef float f32x4 __attribute__((ext_vector_type(4)));

#define TBLK 2048
#define KD 512
#define NH 8
#define MROWS 8192      // 4 batches x 2048

__device__ __forceinline__ u16 f2b(float f){
  u32 u = __builtin_bit_cast(u32, f);
  u = (u + 0x7fffu + ((u >> 16) & 1u)) >> 16;
  return (u16)u;
}

__device__ __forceinline__ u8 f2fp8(float f){
  return (u8)(__builtin_amdgcn_cvt_pk_fp8_f32(f, f, 0, false) & 0xff);
}

__device__ __forceinline__ float gelu_tanh(float x){
  float x3 = x*x*x;
  float t = tanhf(0.7978845608028654f*(x + 0.044715f*x3));
  return 0.5f*x*(1.0f + t);
}

// async global->LDS, 16B per lane; LDS dest is wave-uniform base; HW adds lane*16
__device__ __forceinline__ void glds16(const void* g, void* l){
  __builtin_amdgcn_global_load_lds((const __attribute__((address_space(1))) void*)g,
                                   (__attribute__((address_space(3))) void*)l,
                                   16, 0, 0);
}

// ---------------- elementwise f32 -> bf16 ----------------
__global__ void to_bf16_kernel(const float* __restrict__ in, u16* __restrict__ out, int n4){
  int i = blockIdx.x*256 + threadIdx.x;
  if (i >= n4) return;
  size_t base = (size_t)i*4;
  float4 v = *(const float4*)(in + base);
  uint2 pk;
  pk.x = (u32)f2b(v.x) | ((u32)f2b(v.y) << 16);
  pk.y = (u32)f2b(v.z) | ((u32)f2b(v.w) << 16);
  *(uint2*)(out + base) = pk;
}

// ---- transpose + convert: in R x C f32 -> out C x R bf16 ----
template<bool PERM>
__global__ void transpose_to_bf16(const float* __restrict__ in, u16* __restrict__ out, int R, int C){
  __shared__ float tile[64][65];
  int bc = blockIdx.x*64, br = blockIdx.y*64;
  int tx = threadIdx.x & 63, ty = threadIdx.x >> 6;
  #pragma unroll
  for (int i = 0; i < 64; i += 4)
    tile[ty+i][tx] = in[(size_t)(br+ty+i)*C + bc + tx];
  __syncthreads();
  #pragma unroll
  for (int i = 0; i < 64; i += 4){
    int n = bc + ty + i;
    int np = PERM ? ((n & 7)*512 + (n >> 3)) : n;
    out[(size_t)np*R + br + tx] = f2b(tile[tx][ty+i]);
  }
}

// merged QKV weight transpose (z selects Wq/Wk/Wv), head-grouped row order
__global__ void transpose_qkv3(const float* __restrict__ wq, const float* __restrict__ wk,
                               const float* __restrict__ wv, u16* __restrict__ oq,
                               u16* __restrict__ ok, u16* __restrict__ ov){
  __shared__ float tile[64][65];
  const float* in = (blockIdx.z == 0) ? wq : (blockIdx.z == 1 ? wk : wv);
  u16* out = (blockIdx.z == 0) ? oq : (blockIdx.z == 1 ? ok : ov);
  int bc = blockIdx.x*64, br = blockIdx.y*64;   // C=4096, R=512
  int tx = threadIdx.x & 63, ty = threadIdx.x >> 6;
  #pragma unroll
  for (int i = 0; i < 64; i += 4)
    tile[ty+i][tx] = in[(size_t)(br+ty+i)*4096 + bc + tx];
  __syncthreads();
  #pragma unroll
  for (int i = 0; i < 64; i += 4){
    int n = bc + ty + i;
    int np = (n & 7)*512 + (n >> 3);
    out[(size_t)np*512 + br + tx] = f2b(tile[tx][ty+i]);
  }
}

// ---------------- GEMM: C = A(MxK,bf16) @ Bt(NxK,bf16)^T (round-8 config) ----------------
// MODE 2: out32[row*512+col] = v + bias[col]          (Wu)
// MODE 3: out16[row*2048+col] = bf16(gelu(v+bias))    (FF1)
// MODE 4: out32[row*512+col] = v + bias[col] + resid  (FF2)
// MODE 5: fused QKV split -> bf16 Q,K (scaled) + fp8 V
template<int MODE, int BN>
__launch_bounds__(256, 2)
__global__ void gemm_bf16(const u16* __restrict__ A, int lda,
                          const u16* __restrict__ Bt, int M, int N, int K,
                          const float* __restrict__ bias, const float* __restrict__ resid,
                          float scale, u16* __restrict__ out16, float* __restrict__ out32,
                          u16* __restrict__ k16 = nullptr, u8* __restrict__ v8 = nullptr)
{
  __shared__ alignas(16) u16 At[2][128*32];
  __shared__ alignas(16) u16 Bs[2][BN*32];
  constexpr int MT = (BN == 128) ? 4 : 2;
  constexpr int BU = (BN == 128) ? 2 : 1;
  int ntn = N / BN;
  int tm = blockIdx.x / ntn;
  int tn = blockIdx.x - tm*ntn;
  int m0 = tm << 7, n0 = tn*BN;
  int tid = threadIdx.x;
  int lane = tid & 63;
  int w = tid >> 6;
  int wr = (BN == 128) ? (w >> 1) : w;
  int wc = (BN == 128) ? (w & 1) : 0;
  int rl = lane & 15, gr = lane >> 4;
  int srow = lane >> 2;
  int scol = (lane & 3) ^ ((lane >> 3) & 3);

  f32x4 acc[MT][4];
  #pragma unroll
  for (int m = 0; m < MT; ++m)
    #pragma unroll
    for (int n = 0; n < 4; ++n)
      #pragma unroll
      for (int r = 0; r < 4; ++r) acc[m][n][r] = 0.f;

  auto stage = [&](int buf, int k0){
    #pragma unroll
    for (int i = 0; i < 2; ++i){
      int u = w*2 + i;
      glds16(A + (size_t)(m0 + u*16 + srow)*lda + k0 + scol*8, &At[buf][u*512]);
    }
    #pragma unroll
    for (int i = 0; i < BU; ++i){
      int u = w*BU + i;
      glds16(Bt + (size_t)(n0 + u*16 + srow)*K + k0 + scol*8, &Bs[buf][u*512]);
    }
  };

  stage(0, 0);
  int nsteps = K >> 5;
  for (int s = 0; s < nsteps; ++s){
    int cur = s & 1;
    __syncthreads();
    if (s + 1 < nsteps) stage(cur ^ 1, (s + 1)*32);
    bf16x8 af[MT], bfv[4];
    #pragma unroll
    for (int m = 0; m < MT; ++m){
      int row = wr*MT*16 + m*16 + rl;
      af[m] = *(const bf16x8*)(&At[cur][row*32 + ((gr ^ ((row >> 1) & 3))*8)]);
    }
    #pragma unroll
    for (int n = 0; n < 4; ++n){
      int row = wc*64 + n*16 + rl;
      bfv[n] = *(const bf16x8*)(&Bs[cur][row*32 + ((gr ^ ((row >> 1) & 3))*8)]);
    }
    __builtin_amdgcn_s_setprio(1);
    #pragma unroll
    for (int m = 0; m < MT; ++m)
      #pragma unroll
      for (int n = 0; n < 4; ++n)
        acc[m][n] = __builtin_amdgcn_mfma_f32_16x16x32_bf16(af[m], bfv[n], acc[m][n], 0, 0, 0);
    __builtin_amdgcn_s_setprio(0);
  }

  #pragma unroll
  for (int m = 0; m < MT; ++m){
    #pragma unroll
    for (int n = 0; n < 4; ++n){
      int col = n0 + wc*64 + n*16 + rl;
      #pragma unroll
      for (int r = 0; r < 4; ++r){
        int row = m0 + wr*MT*16 + m*16 + gr*4 + r;
        float v = acc[m][n][r];
        if (MODE == 2){
          out32[(size_t)row*512 + col] = v + bias[col];
        } else if (MODE == 3){
          out16[(size_t)row*2048 + col] = f2b(gelu_tanh(v + bias[col]));
        } else if (MODE == 4){
          out32[(size_t)row*512 + col] = v + bias[col] + resid[(size_t)row*512 + col];
        } else {  // MODE 5: Q,K -> bf16 (scaled); V -> fp8
          if (col < 4096)       out16[(size_t)row*4096 + col]          = f2b(v*scale);
          else if (col < 8192)  k16[(size_t)row*4096 + (col & 4095)]   = f2b(v*scale);
          else                  v8[(size_t)row*4096 + (col & 4095)]    = f2fp8(v);
        }
      }
    }
  }
}

// ---------------- V tile-pack (fp8): vg8[(bl*2048+t)*4096 + h*512+d] ->
// vt8 region (bh*64+t0/32)*16384, byte = (d>>4)*512 + ((t&31)>>3)*128 + (d&15)*8 + (t&7)
__global__ void vtrans_kernel(const u8* __restrict__ vg8, u8* __restrict__ vt8){
  __shared__ alignas(16) u8 tile[64][80];
  int t0 = blockIdx.x*64;
  int d0 = blockIdx.y*64;
  int bh = blockIdx.z;
  int bl = bh >> 3, h = bh & 7;
  int tid = threadIdx.x;
  {
    int row = tid >> 2, cb = (tid & 3)*16;
    *(uint4*)(&tile[row][cb]) =
        *(const uint4*)(vg8 + (size_t)(bl*TBLK + t0 + row)*4096 + h*512 + d0 + cb);
  }
  __syncthreads();
  #pragma unroll
  for (int it = 0; it < 2; ++it){
    int o = it*256 + tid;
    int rl = o & 15, gr = (o >> 4) & 3, gl = (o >> 6) & 3, st2 = (o >> 8) & 1;
    int d_local = gl*16 + rl;
    int tb = st2*32 + gr*8;
    alignas(8) u8 tmp[8];
    #pragma unroll
    for (int j = 0; j < 8; ++j) tmp[j] = tile[tb + j][d_local];
    size_t region = ((size_t)bh*64 + (t0 >> 5) + st2)*16384;
    int g = (d0 >> 4) + gl;
    *(uint2*)(vt8 + region + g*512 + gr*128 + rl*8) = *(const uint2*)tmp;
  }
}

// ---------------- flash attention: bf16 QK^T + fp8 P,V ----------------
// grid: (nbh [x -> XCD=bh%8], qt=16). 8 waves x 16 q-rows = 128 rows/block.
// dbuf: K bf16 (XOR source swizzle) + V fp8 (pre-tiled global, linear stage).
// Lazy-max THR=5 => P <= e^5=148 < 448 fits e4m3 WITHOUT pre-scale (no subnormals).
__launch_bounds__(512, 2)
__global__ void flash_attn(const u16* __restrict__ qg, const u16* __restrict__ kg,
                           const u8* __restrict__ vt8, u16* __restrict__ ctx)
{
  int bh = blockIdx.x;
  int qt = blockIdx.y;
  int bl = bh >> 3, h = bh & 7;
  int tid = threadIdx.x;
  int lane = tid & 63, w = tid >> 6;
  int rl = lane & 15, gr = lane >> 4;
  const u16* Qb = qg + (size_t)bl*TBLK*4096 + h*512;
  const u16* Kb = kg + (size_t)bl*TBLK*4096 + h*512;
  const u8*  Vb = vt8 + (size_t)bh*64*16384;

  __shared__ alignas(16) u16 Ka[2][32*512];   // 2 x 32KB bf16
  __shared__ alignas(16) u8  Va[2][16384];    // 2 x 16KB fp8 (tiled)
  __shared__ alignas(16) u8  Pl[8][640];      // 16 q-rows x stride 40, per wave
  // total ~101KB -> 1 block/CU, 8 waves

  int q0 = qt*128 + w*16;
  bf16x8 qf[16];
  #pragma unroll
  for (int kc = 0; kc < 16; ++kc)
    qf[kc] = *(const bf16x8*)(Qb + (size_t)(q0 + rl)*4096 + kc*32 + gr*8);

  f32x4 o[32];
  #pragma unroll
  for (int n = 0; n < 32; ++n)
    #pragma unroll
    for (int r = 0; r < 4; ++r) o[n][r] = 0.f;
  float mrow[4] = {-1e30f, -1e30f, -1e30f, -1e30f};
  float lsum[4] = {0.f, 0.f, 0.f, 0.f};

  auto stage = [&](int buf, int s0){
    #pragma unroll
    for (int i = 0; i < 4; ++i){
      int wl = w*4 + i;                       // K row 0..31, 1KB each
      glds16(Kb + (size_t)(s0 + wl)*4096 + (size_t)((lane ^ (wl & 7))*8),
             &Ka[buf][wl*512]);
    }
    #pragma unroll
    for (int i = 0; i < 2; ++i){
      int u = w*2 + i;                        // V unit 0..15, 1KB each, linear
      glds16(Vb + (size_t)(s0 >> 5)*16384 + u*1024 + lane*16, &Va[buf][u*1024]);
    }
  };

  stage(0, 0);

  for (int t = 0; t < 64; ++t){
    int cur = t & 1;
    __syncthreads();                          // vmcnt(0) drain -> buf[cur] ready+visible

    // QK^T (bf16, exact scores)
    f32x4 sA[2];
    #pragma unroll
    for (int n = 0; n < 2; ++n)
      #pragma unroll
      for (int r = 0; r < 4; ++r) sA[n][r] = 0.f;
    __builtin_amdgcn_s_setprio(1);
    #pragma unroll
    for (int kc = 0; kc < 16; ++kc){
      #pragma unroll
      for (int n = 0; n < 2; ++n){
        int rowS = n*16 + rl;
        bf16x8 kf = *(const bf16x8*)(&Ka[cur][rowS*512 + (((kc*4 + gr) ^ (rowS & 7))*8)]);
        sA[n] = __builtin_amdgcn_mfma_f32_16x16x32_bf16(qf[kc], kf, sA[n], 0, 0, 0);
      }
    }
    __builtin_amdgcn_s_setprio(0);

    if (t < 63) stage(cur ^ 1, (t + 1)*32);   // async prefetch; drains at next barrier

    // lazy-max online softmax (THR=5: P <= e^5 fits fp8 e4m3 normal range)
    bool updl = false;
    #pragma unroll
    for (int n = 0; n < 2; ++n)
      #pragma unroll
      for (int r = 0; r < 4; ++r) updl |= (sA[n][r] > mrow[r] + 5.0f);
    if (__any(updl)){
      float pm[4], fr[4];
      #pragma unroll
      for (int r = 0; r < 4; ++r) pm[r] = fmaxf(sA[0][r], sA[1][r]);
      #pragma unroll
      for (int m = 1; m < 16; m <<= 1)
        #pragma unroll
        for (int r = 0; r < 4; ++r) pm[r] = fmaxf(pm[r], __shfl_xor(pm[r], m));
      #pragma unroll
      for (int r = 0; r < 4; ++r){
        float mn = fmaxf(mrow[r], pm[r]);
        fr[r] = __expf(mrow[r] - mn);
        mrow[r] = mn;
        lsum[r] *= fr[r];
      }
      #pragma unroll
      for (int n = 0; n < 32; ++n)
        #pragma unroll
        for (int r = 0; r < 4; ++r) o[n][r] *= fr[r];
    }

    float p0[4], p1[4];
    #pragma unroll
    for (int r = 0; r < 4; ++r){
      p0[r] = __expf(sA[0][r] - mrow[r]);
      p1[r] = __expf(sA[1][r] - mrow[r]);
      lsum[r] += p0[r] + p1[r];
    }

    // P -> fp8 (no pre-scale), stride-40 rows (conflict-free b64 reads)
    u8* pw = &Pl[w][0];
    #pragma unroll
    for (int r = 0; r < 4; ++r){
      int tq = gr*4 + r;
      pw[tq*40 + rl]      = f2fp8(p0[r]);
      pw[tq*40 + 16 + rl] = f2fp8(p1[r]);
    }
    asm volatile("s_waitcnt lgkmcnt(0)" ::: "memory");
    i64 pa = *(const i64*)(pw + rl*40 + gr*8);

    // PV (fp8): vf conflict-free (tiled layout)
    __builtin_amdgcn_s_setprio(1);
    #pragma unroll
    for (int n = 0; n < 32; ++n){
      i64 vf = *(const i64*)(&Va[cur][n*512 + gr*128 + rl*8]);
      o[n] = __builtin_amdgcn_mfma_f32_16x16x32_fp8_fp8(pa, vf, o[n], 0, 0, 0);
    }
    __builtin_amdgcn_s_setprio(0);
  }

  #pragma unroll
  for (int m = 1; m < 16; m <<= 1)
    #pragma unroll
    for (int r = 0; r < 4; ++r) lsum[r] += __shfl_xor(lsum[r], m);

  #pragma unroll
  for (int n = 0; n < 32; ++n){
    int d = n*16 + rl;
    #pragma unroll
    for (int r = 0; r < 4; ++r){
      int tq = q0 + gr*4 + r;
      float v = o[n][r] / lsum[r];
      ctx[((size_t)(bl*TBLK + tq))*4096 + h*512 + d] = f2b(v);
    }
  }
}

// ---------------- LayerNorm over (T,k) per batch ----------------
__global__ void reduce_ms(const float* __restrict__ in, float* __restrict__ part, int nblk){
  int b = blockIdx.y;
  const float4* p = (const float4*)(in + (size_t)b*TBLK*KD);
  int n4 = TBLK*KD/4;
  float s = 0.f, s2 = 0.f;
  for (int i = blockIdx.x*blockDim.x + threadIdx.x; i < n4; i += nblk*blockDim.x){
    float4 v = p[i];
    s  += v.x + v.y + v.z + v.w;
    s2 += v.x*v.x + v.y*v.y + v.z*v.z + v.w*v.w;
  }
  #pragma unroll
  for (int m = 1; m < 64; m <<= 1){ s += __shfl_xor(s, m); s2 += __shfl_xor(s2, m); }
  __shared__ float sh[8];
  int w = threadIdx.x >> 6;
  if ((threadIdx.x & 63) == 0){ sh[w] = s; sh[4 + w] = s2; }
  __syncthreads();
  if (threadIdx.x == 0){
    float a = 0.f, a2 = 0.f;
    for (int i = 0; i < 4; ++i){ a += sh[i]; a2 += sh[4 + i]; }
    part[((size_t)b*nblk + blockIdx.x)*2]     = a;
    part[((size_t)b*nblk + blockIdx.x)*2 + 1] = a2;
  }
}

__global__ void finalize_ms(const float* __restrict__ part, float* __restrict__ stats, int nblk){
  int b = blockIdx.x;
  float s = 0.f, s2 = 0.f;
  for (int i = threadIdx.x; i < nblk; i += 64){
    s  += part[((size_t)b*nblk + i)*2];
    s2 += part[((size_t)b*nblk + i)*2 + 1];
  }
  #pragma unroll
  for (int m = 1; m < 64; m <<= 1){ s += __shfl_xor(s, m); s2 += __shfl_xor(s2, m); }
  if (threadIdx.x == 0){
    float inv_n = 1.0f/((float)TBLK*KD);
    float mean = s*inv_n;
    float var = s2*inv_n - mean*mean;
    stats[b*2] = mean;
    stats[b*2 + 1] = 1.0f/sqrtf(var + 1e-5f);
  }
}

__global__ void ln1_apply(const float* __restrict__ attn, const float* __restrict__ x,
                          const float* __restrict__ stats, const float* __restrict__ gs,
                          const float* __restrict__ go, float* __restrict__ x1f,
                          u16* __restrict__ x1b){
  int g = blockIdx.x*256 + threadIdx.x;
  size_t base = (size_t)g*4;
  int b = (int)(base >> 20);
  int col = (int)(base & (KD - 1));
  float mean = stats[b*2], inv = stats[b*2 + 1];
  float4 a  = *(const float4*)(attn + base);
  float4 xr = *(const float4*)(x + base);
  float4 sc = *(const float4*)(gs + col);
  float4 of = *(const float4*)(go + col);
  float4 r;
  r.x = sc.x*(a.x - mean)*inv + of.x + xr.x;
  r.y = sc.y*(a.y - mean)*inv + of.y + xr.y;
  r.z = sc.z*(a.z - mean)*inv + of.z + xr.z;
  r.w = sc.w*(a.w - mean)*inv + of.w + xr.w;
  *(float4*)(x1f + base) = r;
  uint2 pk;
  pk.x = (u32)f2b(r.x) | ((u32)f2b(r.y) << 16);
  pk.y = (u32)f2b(r.z) | ((u32)f2b(r.w) << 16);
  *(uint2*)(x1b + base) = pk;
}

__global__ void ln2_apply(const float* __restrict__ y, const float* __restrict__ stats,
                          const float* __restrict__ gs, const float* __restrict__ go,
                          float* __restrict__ outp){
  int g = blockIdx.x*256 + threadIdx.x;
  size_t base = (size_t)g*4;
  int b = (int)(base >> 20);
  int col = (int)(base & (KD - 1));
  float mean = stats[b*2], inv = stats[b*2 + 1];
  float4 v  = *(const float4*)(y + base);
  float4 sc = *(const float4*)(gs + col);
  float4 of = *(const float4*)(go + col);
  float4 r;
  r.x = sc.x*(v.x - mean)*inv + of.x;
  r.y = sc.y*(v.y - mean)*inv + of.y;
  r.z = sc.z*(v.z - mean)*inv + of.z;
  r.w = sc.w*(v.w - mean)*inv + of.w;
  *(float4*)(outp + base) = r;
}

extern "C" void kernel_launch(void* const* d_in, const int* in_sizes, int n_in,
                              void* d_out, int out_size, void* d_ws, size_t ws_size,
                              hipStream_t stream)
{
  const float* x  = (const float*)d_in[0];
  const float* Wq = (const float*)d_in[1];
  const float* Wk = (const float*)d_in[2];
  const float* Wv = (const float*)d_in[3];
  const float* Wu = (const float*)d_in[4];
  const float* bu = (const float*)d_in[5];
  const float* g1 = (const float*)d_in[6];
  const float* o1 = (const float*)d_in[7];
  const float* W1 = (const float*)d_in[8];
  const float* b1 = (const float*)d_in[9];
  const float* W2 = (const float*)d_in[10];
  const float* b2 = (const float*)d_in[11];
  const float* g2 = (const float*)d_in[12];
  const float* o2 = (const float*)d_in[13];
  float* outp = (float*)d_out;
  (void)in_sizes; (void)n_in; (void)out_size;

  char* ws = (char*)d_ws;
  size_t off = 0;
  auto take = [&](size_t bytes)->char*{
    char* p = ws + off; off += (bytes + 255) & ~(size_t)255; return p;
  };
  u16* x16 = (u16*)take((size_t)MROWS*KD*2);
  u16* wqt = (u16*)take((size_t)4096*512*2);
  u16* wkt = (u16*)take((size_t)4096*512*2);
  u16* wvt = (u16*)take((size_t)4096*512*2);
  u16* wut = (u16*)take((size_t)512*4096*2);
  u16* w1t = (u16*)take((size_t)2048*512*2);
  u16* w2t = (u16*)take((size_t)512*2048*2);
  float* red = (float*)take((size_t)(4*256*2 + 8)*4);
  float* stats = red + 4*256*2;
  size_t fixed_end = off;

  // variable: qg,kg (cm*8192 B), vg8,vt8 (cm*4096 B), ctx (cm*8192 B) = cm*32768 B
  size_t need1 = fixed_end + (size_t)8192*32768 + 4096;
  int cm = (ws_size >= need1) ? 8192 : 4096;
  int nchunks = MROWS / cm;
  u16* qg  = (u16*)take((size_t)cm*8192);
  u16* kg  = (u16*)take((size_t)cm*8192);
  u8*  vg8 = (u8*)take((size_t)cm*4096);
  u8*  vt8 = (u8*)take((size_t)cm*4096);
  u16* ctx = (u16*)take((size_t)cm*8192);

  // lifetime-disjoint aliases (ctx NOT aliased with attn: Wu reads ctx while writing attn)
  char* qc = (char*)qg;                        // qg dead after flash
  float* attn = (float*)qc;                    // cm*2048 B
  float* x1f  = (float*)(qc + (size_t)cm*2048);// cm*2048 B
  u16*   x1b  = (u16*) (qc + (size_t)cm*4096); // cm*1024 B
  float* yb   = (float*)(qc + (size_t)cm*5120);// cm*2048 B (7168*cm <= 8192*cm)
  u16*   fwd  = kg;                            // kg dead after flash; cm*4096 B used

  const float qscale = 0.21022410381342865f;  // 512^(-1/4)

  to_bf16_kernel<<<dim3(4096), dim3(256), 0, stream>>>(x, x16, MROWS*KD/4);
  transpose_qkv3<<<dim3(64, 8, 3), dim3(256), 0, stream>>>(Wq, Wk, Wv, wqt, wkt, wvt);
  transpose_to_bf16<false><<<dim3(8, 64), dim3(256), 0, stream>>>(Wu, wut, 4096, 512);
  transpose_to_bf16<false><<<dim3(32, 8), dim3(256), 0, stream>>>(W1, w1t, 512, 2048);
  transpose_to_bf16<false><<<dim3(8, 32), dim3(256), 0, stream>>>(W2, w2t, 2048, 512);

  int nb = cm / TBLK;
  int nbh = nb * NH;
  for (int chunk = 0; chunk < nchunks; ++chunk){
    const u16* xc  = x16 + (size_t)chunk*cm*KD;
    const float* xf = x  + (size_t)chunk*cm*KD;

    // fused QKV projection: Bt = [wqt|wkt|wvt], N = 12288; Q,K bf16, V fp8
    gemm_bf16<5,128><<<dim3((cm/128)*96), dim3(256), 0, stream>>>(xc, 512, wqt, cm, 12288, 512,
                                                        nullptr, nullptr, qscale,
                                                        qg, nullptr, kg, vg8);
    vtrans_kernel<<<dim3(32, 8, nbh), dim3(256), 0, stream>>>(vg8, vt8);
    flash_attn<<<dim3(nbh, 16), dim3(512), 0, stream>>>(qg, kg, vt8, ctx);

    gemm_bf16<2,64><<<dim3((cm/128)*8), dim3(256), 0, stream>>>(ctx, 4096, wut, cm, 512, 4096,
                                                       bu, nullptr, 1.0f, nullptr, attn);
    reduce_ms<<<dim3(256, nb), dim3(256), 0, stream>>>(attn, red, 256);
    finalize_ms<<<dim3(nb), dim3(64), 0, stream>>>(red, stats, 256);
    ln1_apply<<<dim3(cm/2), dim3(256), 0, stream>>>(attn, xf, stats, g1, o1, x1f, x1b);

    gemm_bf16<3,128><<<dim3((cm/128)*16), dim3(256), 0, stream>>>(x1b, 512, w1t, cm, 2048, 512,
                                                        b1, nullptr, 1.0f, fwd, nullptr);
    gemm_bf16<4,64><<<dim3((cm/128)*8), dim3(256), 0, stream>>>(fwd, 2048, w2t, cm, 512, 2048,
                                                       b2, x1f, 1.0f, nullptr, yb);
    reduce_ms<<<dim3(256, nb), dim3(256), 0, stream>>>(yb, red, 256);
    finalize_ms<<<dim3(nb), dim3(64), 0, stream>>>(red, stats, 256);
    ln2_apply<<<dim3(cm/2), dim3(256), 0, stream>>>(yb, stats, g2, o2, outp + (size_t)chunk*cm*KD);
  }
}